// Round 9
// baseline (1433.368 us; speedup 1.0000x reference)
//
#include <hip/hip_runtime.h>
#include <hip/hip_bf16.h>
#include <math.h>
#include <stdint.h>

// HolomorphicEqProp: B=4096, D_IN=H=1024, D_OUT=256, steps=30.
// Round-18: R17's per-wave design on the PROVEN 256-block grid.
//  R17 failed with absmax 2.69 + fast completion: 512-block coop launch at
//  the co-residency boundary with ~130-VGPR waves most likely REJECTED the
//  launch (unchecked error) -> rnn never ran, gemm read uninit hB. Lesson:
//  don't change grid shape and barrier protocol in one round.
//  R18: 256 blocks x 1024 threads (launch shape proven by R12/R14), barrier
//  + group mapping + publish/fastflag VERBATIM R16 (passed, 647 us).
//  Per-wave (the actual experiment — TLP with full pipeline depth):
//   16 waves = 4/SIMD; wave w: m-sub w&7 (32 rows), n-sub w>>3 (32 cols);
//   acc 2x2, dual-m ring-8 global h prefetch, paired {4 ds_read -> 8 MFMA}
//   phases, R16 conflict-free tiled LDS (per-wave base nw*32768 +
//   compile-time offsets). Fixes all three diagnosed R12 regressors
//   (ring-4 lead, 3.1e7 conflicts, 4-MFMA phases) at 4 waves/SIMD.

#define EPSF 1e-12f

typedef short bf16x8 __attribute__((ext_vector_type(8)));
typedef float f32x4 __attribute__((ext_vector_type(4)));

struct Mods { float m[32]; };

__device__ __forceinline__ unsigned short f2bf(float f) {
  union { float f; unsigned u; } v; v.f = f;
  unsigned r = v.u + 0x7FFFu + ((v.u >> 16) & 1u);  // RNE
  return (unsigned short)(r >> 16);
}

// packed f32x2 -> bf16x2 (RNE), single VALU op
__device__ __forceinline__ unsigned cvt_pk_bf16(float lo, float hi) {
  unsigned r;
  asm("v_cvt_pk_bf16_f32 %0, %1, %2" : "=v"(r) : "v"(lo), "v"(hi));
  return r;
}

// tanh(x) = 1 - 2/(exp(2x)+1). Saturates exactly; abs err ~1e-7 << bf16 eps.
__device__ __forceinline__ float tanh_fast(float x) {
  float e = __expf(2.0f * x);
  float r = __builtin_amdgcn_rcpf(e + 1.0f);
  return fmaf(-2.0f, r, 1.0f);
}

// async global->LDS (only in gemm_bt0: R1-validated pattern)
__device__ __forceinline__ void async16(const void* g, void* l) {
  __builtin_amdgcn_global_load_lds(
      (__attribute__((address_space(1))) void*)(uintptr_t)(g),
      (__attribute__((address_space(3))) void*)(unsigned)(uintptr_t)(l),
      16, 0, 0);
}

__device__ __forceinline__ float block_reduce_sum(float x) {
#pragma unroll
  for (int o = 32; o > 0; o >>= 1) x += __shfl_down(x, o, 64);
  __shared__ float sm[8];
  int lane = threadIdx.x & 63, w = threadIdx.x >> 6;
  if (lane == 0) sm[w] = x;
  __syncthreads();
  float t = 0.f;
  if (threadIdx.x == 0) {
    int nw = (int)(blockDim.x >> 6);
    for (int i = 0; i < nw; ++i) t += sm[i];
  }
  return t;
}

// ---------------- fused spectral-norm setup (fp32, exact) ----------------

__global__ void spec_col3(const float* __restrict__ Wi, const float* __restrict__ Wr,
                          const float* __restrict__ Wo, const float* __restrict__ ui,
                          const float* __restrict__ ur, const float* __restrict__ uo,
                          float* __restrict__ v) {
  int z = blockIdx.z;
  const float* W = (z == 0) ? Wi : (z == 1) ? Wr : Wo;
  const float* u = (z == 0) ? ui : (z == 1) ? ur : uo;
  int M = (z == 2) ? 256 : 1024;
  int i0 = blockIdx.y * 64;
  if (i0 >= M) return;
  int j = blockIdx.x * blockDim.x + threadIdx.x;
  float acc = 0.f;
  for (int i = i0; i < i0 + 64; ++i)
    acc += W[(size_t)i * 1024 + j] * u[i];
  atomicAdd(&v[z * 1024 + j], acc);
}

__global__ void norm3(const float* __restrict__ v, float* __restrict__ S) {
  int z = blockIdx.x;
  float acc = 0.f;
  for (int i = threadIdx.x; i < 1024; i += blockDim.x) {
    float x = v[z * 1024 + i];
    acc += x * x;
  }
  float t = block_reduce_sum(acc);
  if (threadIdx.x == 0) S[z] = t;
}

__global__ void rowsq3(const float* __restrict__ Wi, const float* __restrict__ Wr,
                       const float* __restrict__ Wo, const float* __restrict__ v,
                       float* __restrict__ S) {
  int bid = blockIdx.x;
  int z = (bid < 1024) ? 0 : (bid < 2048) ? 1 : 2;
  int row = bid - ((z == 0) ? 0 : (z == 1) ? 1024 : 2048);
  const float* W = (z == 0) ? Wi : (z == 1) ? Wr : Wo;
  const float* vv = v + z * 1024;
  float acc = 0.f;
  for (int j = threadIdx.x; j < 1024; j += blockDim.x)
    acc += W[(size_t)row * 1024 + j] * vv[j];
  float r = block_reduce_sum(acc);
  if (threadIdx.x == 0) atomicAdd(&S[3 + z], r * r);
}

__global__ void spec_finalize(float* S) {
  int m = threadIdx.x;
  if (m < 3) {
    float nv = sqrtf(S[m]);
    float inv = 1.f / (nv + EPSF);
    float u2sq = S[3 + m] * inv * inv;
    float nu = sqrtf(u2sq);
    float sigma = u2sq / (nu + EPSF);
    S[6 + m] = 1.f / sigma;
  }
}

__device__ __forceinline__ ushort4 cvt4e(float4 w, float s) {
  ushort4 r;
  r.x = f2bf(w.x * s); r.y = f2bf(w.y * s); r.z = f2bf(w.z * s); r.w = f2bf(w.w * s);
  return r;
}

__global__ void cvt_all(const float4* __restrict__ Wi, const float4* __restrict__ Wr,
                        const float4* __restrict__ Wo, const float4* __restrict__ x,
                        const float* __restrict__ S,
                        ushort4* __restrict__ oWi, ushort4* __restrict__ oWr,
                        ushort4* __restrict__ oWo, ushort4* __restrict__ ox) {
  float s6 = S[6], s7 = S[7], s8 = S[8];
  int stride = gridDim.x * blockDim.x;
  int t0 = blockIdx.x * blockDim.x + threadIdx.x;
  for (int i = t0; i < 262144; i += stride) oWi[i] = cvt4e(Wi[i], s6);
  for (int i = t0; i < 262144; i += stride) oWr[i] = cvt4e(Wr[i], s7);
  for (int i = t0; i < 65536; i += stride) oWo[i] = cvt4e(Wo[i], s8);
  for (int i = t0; i < 1048576; i += stride) ox[i] = cvt4e(x[i], 1.0f);
}

// C = A[M,K] . B[N,K]^T + bias[n], fp32 out. 64x128 tile (validated R5/R7).
__global__ __launch_bounds__(256) void gemm_bt0(
    const unsigned short* __restrict__ A, const unsigned short* __restrict__ B,
    const float* __restrict__ bias, float* __restrict__ outF,
    int M, int N, int K) {
  constexpr int BM = 64, BN = 128, BK = 32;
  __shared__ __align__(16) unsigned short As[BM * BK];
  __shared__ __align__(16) unsigned short Bs[BN * BK];
  const int tid = threadIdx.x;
  const int wave = tid >> 6, lane = tid & 63;
  const int m0 = blockIdx.x * BM, n0 = blockIdx.y * BN;
  const int wm = (wave >> 1) * 32, wn = (wave & 1) * 64;
  const int lrow = lane & 15, quad = lane >> 4;

  f32x4 acc[2][4] = {};

  for (int k0 = 0; k0 < K; k0 += BK) {
    {
      int e = tid * 8;
      int r = e >> 5, c = e & 31;
      async16(&A[(size_t)(m0 + r) * K + k0 + c], &As[e]);
#pragma unroll
      for (int inst = 0; inst < 2; ++inst) {
        int eb = inst * 2048 + tid * 8;
        int rb = eb >> 5, cb = eb & 31;
        async16(&B[(size_t)(n0 + rb) * K + k0 + cb], &Bs[eb]);
      }
    }
    __syncthreads();

    bf16x8 af[2], bfr[4];
#pragma unroll
    for (int i = 0; i < 2; ++i)
      af[i] = *(const bf16x8*)&As[(wm + i * 16 + lrow) * BK + quad * 8];
#pragma unroll
    for (int j = 0; j < 4; ++j)
      bfr[j] = *(const bf16x8*)&Bs[(wn + j * 16 + lrow) * BK + quad * 8];
#pragma unroll
    for (int i = 0; i < 2; ++i)
#pragma unroll
      for (int j = 0; j < 4; ++j)
        acc[i][j] = __builtin_amdgcn_mfma_f32_16x16x32_bf16(af[i], bfr[j], acc[i][j], 0, 0, 0);
    __syncthreads();
  }

#pragma unroll
  for (int i = 0; i < 2; ++i)
#pragma unroll
    for (int j = 0; j < 4; ++j) {
      int col = n0 + wn + j * 16 + lrow;
      float bv = bias[col];
#pragma unroll
      for (int r = 0; r < 4; ++r) {
        int row = m0 + wm + i * 16 + quad * 4 + r;
        outF[(size_t)row * N + col] = acc[i][j][r] + bv;
      }
    }
}

// ---------------- cooperative RNN ----------------

// Tiled conflict-free LDS (R16-validated): ws[nf][kc][lane][8 shorts],
// nf 0..3, kc 0..31. Subtile (nf,kc) = rows nf*16..+15, cols kc*32..+31 of
// the 64x1024 Wr/Wi slice, 1 KB contiguous, lane l reads bytes l*16..+15.
// 1024 threads: each loads 64 shorts (row r = tid&63, segment s = tid>>6).
__device__ __forceinline__ void load_ws(const unsigned short* __restrict__ src,
                                        unsigned short* ws, int tid) {
  int r = tid & 63, s = tid >> 6;     // row r (0..63), col segment s (0..15)
  int nf = r >> 4, lrow = r & 15;
  const unsigned short* p = src + (size_t)r * 1024 + s * 64;
#pragma unroll
  for (int j = 0; j < 8; ++j) {
    int c = s * 64 + j * 8;
    int kc = c >> 5, quad = (c >> 3) & 3;
    *(bf16x8*)&ws[((nf * 32 + kc) * 64 + (lrow + 16 * quad)) * 8] =
        *(const bf16x8*)(p + j * 8);
  }
}

// K-sweep, per-wave tile 32Mx32N (acc 2x2), paired phases {4 ds_read ->
// 8 MFMA}, ring-8 dual m-stream. wslw = ws + lane*8 + nw*32768 (per-wave
// tiled base; frag (nfl,kc) at wslw + (nfl*32+kc)*512). All ring/buffer
// indices compile-time (rule #20).
__device__ __forceinline__ void ksweep(const unsigned short* __restrict__ a0p,
                                       const unsigned short* __restrict__ a1p,
                                       const unsigned short* wslw,
                                       f32x4 acc[2][2]) {
  bf16x8 pa0[8], pa1[8];
#pragma unroll
  for (int i = 0; i < 8; ++i) {
    pa0[i] = *(const bf16x8*)(a0p + i * 32);
    pa1[i] = *(const bf16x8*)(a1p + i * 32);
  }
#pragma unroll 1
  for (int kb = 0; kb < 32; kb += 8) {
#define PAIR(OFF)                                                                \
    {                                                                            \
      const int kc = kb + (OFF);                                                 \
      bf16x8 b00 = *(const bf16x8*)(wslw + (kc) * 512);                          \
      bf16x8 b10 = *(const bf16x8*)(wslw + (32 + kc) * 512);                     \
      bf16x8 b01 = *(const bf16x8*)(wslw + (kc + 1) * 512);                      \
      bf16x8 b11 = *(const bf16x8*)(wslw + (32 + kc + 1) * 512);                 \
      bf16x8 a00 = pa0[(OFF) & 7], a10 = pa1[(OFF) & 7];                         \
      bf16x8 a01 = pa0[((OFF) + 1) & 7], a11 = pa1[((OFF) + 1) & 7];             \
      pa0[(OFF) & 7] = *(const bf16x8*)(a0p + ((kc + 8) & 31) * 32);             \
      pa1[(OFF) & 7] = *(const bf16x8*)(a1p + ((kc + 8) & 31) * 32);             \
      pa0[((OFF) + 1) & 7] = *(const bf16x8*)(a0p + ((kc + 9) & 31) * 32);       \
      pa1[((OFF) + 1) & 7] = *(const bf16x8*)(a1p + ((kc + 9) & 31) * 32);       \
      __builtin_amdgcn_s_setprio(1);                                             \
      acc[0][0] = __builtin_amdgcn_mfma_f32_16x16x32_bf16(b00, a00, acc[0][0], 0, 0, 0); \
      acc[1][0] = __builtin_amdgcn_mfma_f32_16x16x32_bf16(b00, a10, acc[1][0], 0, 0, 0); \
      acc[0][1] = __builtin_amdgcn_mfma_f32_16x16x32_bf16(b10, a00, acc[0][1], 0, 0, 0); \
      acc[1][1] = __builtin_amdgcn_mfma_f32_16x16x32_bf16(b10, a10, acc[1][1], 0, 0, 0); \
      acc[0][0] = __builtin_amdgcn_mfma_f32_16x16x32_bf16(b01, a01, acc[0][0], 0, 0, 0); \
      acc[1][0] = __builtin_amdgcn_mfma_f32_16x16x32_bf16(b01, a11, acc[1][0], 0, 0, 0); \
      acc[0][1] = __builtin_amdgcn_mfma_f32_16x16x32_bf16(b11, a01, acc[0][1], 0, 0, 0); \
      acc[1][1] = __builtin_amdgcn_mfma_f32_16x16x32_bf16(b11, a11, acc[1][1], 0, 0, 0); \
      __builtin_amdgcn_s_setprio(0);                                             \
    }
    PAIR(0) PAIR(2) PAIR(4) PAIR(6)
#undef PAIR
  }
}

// ---- slow/fallback barrier (agent scope, R9-validated form) ----
__device__ __forceinline__ void group_barrier(unsigned* ctr, unsigned target) {
  __syncthreads();  // all waves' stores issued & drained to L2
  if (threadIdx.x == 0) {
    __hip_atomic_fetch_add(ctr, 1u, __ATOMIC_RELEASE, __HIP_MEMORY_SCOPE_AGENT);
    while (__hip_atomic_load(ctr, __ATOMIC_RELAXED, __HIP_MEMORY_SCOPE_AGENT) < target)
      __builtin_amdgcn_s_sleep(2);
    (void)__hip_atomic_load(ctr, __ATOMIC_ACQUIRE, __HIP_MEMORY_SCOPE_AGENT);
  }
  __syncthreads();
}

// ---- fast barrier (group verified XCD-homogeneous): h stays in XCD L2 ----
// (R10-validated: WRITE_SIZE 246 MB -> 22 MB.) Relaxed MALL signal/poll, one
// L1-only invalidate (buffer_inv sc0) on the consumer.
__device__ __forceinline__ void group_barrier_l2(unsigned* ctr, unsigned target) {
  __syncthreads();  // h stores of all 16 waves now visible in XCD L2
  if (threadIdx.x == 0) {
    __hip_atomic_fetch_add(ctr, 1u, __ATOMIC_RELAXED, __HIP_MEMORY_SCOPE_AGENT);
    while (__hip_atomic_load(ctr, __ATOMIC_RELAXED, __HIP_MEMORY_SCOPE_AGENT) < target)
      __builtin_amdgcn_s_sleep(2);
    asm volatile("buffer_inv sc0" ::: "memory");  // invalidate this CU's L1 only
  }
  __syncthreads();
}

// 256 blocks x 1024 threads, 1 block/CU (LDS 128KB), 16 waves = 4/SIMD.
// Block (mt,nt): mt = (bid&7)*2+((bid>>3)&1), nt = bid>>4 (R16 mapping).
// M rows [mt*256,+256), N cols [nt*64,+64). Wave w: m-sub w&7 (32 rows),
// n-sub w>>3 (32 cols). Group = blocks sharing mt (bid&15), closed under
// the h dependency, swizzled onto one XCD.
// Barrier slot layout (128 B): [0]=step ctr, [1]=publish, [2]=XCD mask.
__global__ __launch_bounds__(1024, 4) void rnn_coop(
    const unsigned short* __restrict__ x_bf,  // [4096][1024] bf16
    const unsigned short* __restrict__ Wi,    // [1024][1024] bf16 (scaled)
    const unsigned short* __restrict__ Wr,    // [1024][1024] bf16 (scaled)
    const float* __restrict__ b_in,
    const float* __restrict__ b_rec,
    unsigned short* __restrict__ hA,
    unsigned short* __restrict__ hB,
    unsigned* __restrict__ bar,
    Mods mods) {
  __shared__ __align__(16) unsigned short ws[4 * 32 * 512];  // 128 KB tiled
  __shared__ unsigned fastflag;

  const int tid = threadIdx.x;
  const int w = tid >> 6, lane = tid & 63;
  const int lrow = lane & 15, quad = lane >> 4;
  const int mw = w & 7, nw = w >> 3;   // wave m-sub (0..7), n-sub (0..1)
  const int bid = (int)blockIdx.x;
  const int mt = (bid & 7) * 2 + ((bid >> 3) & 1);
  const int nt = bid >> 4;
  const int gid = bid & 15;
  const int m0 = mt * 256 + mw * 32;
  const int n0 = nt * 64;
  const int ncol0 = n0 + nw * 32;      // wave's first output column
  unsigned* ctr = bar + gid * 32;      // 128 B per group
  const unsigned short* wslw = ws + lane * 8 + nw * 32768;  // per-wave base

  // ---- publish this block's physical XCD at entry (R10 protocol) ----
  if (tid == 0) {
    unsigned xcc;
    asm volatile("s_getreg_b32 %0, hwreg(HW_REG_XCC_ID)" : "=s"(xcc));
    __hip_atomic_fetch_or(ctr + 2, 1u << (xcc & 15u), __ATOMIC_RELAXED,
                          __HIP_MEMORY_SCOPE_AGENT);
    __hip_atomic_fetch_add(ctr + 1, 1u, __ATOMIC_RELEASE, __HIP_MEMORY_SCOPE_AGENT);
  }

  // per-lane biases: n = ncol0 + nfl*16 + quad*4 + r  (swapped D-layout)
  float4 brec4[2];
#pragma unroll
  for (int nfl = 0; nfl < 2; ++nfl)
    brec4[nfl] = *(const float4*)&b_rec[ncol0 + nfl * 16 + quad * 4];

  // ---- phase A: xproj slice (registers) via Wi slice in ws ----
  load_ws(Wi + (size_t)n0 * 1024, ws, tid);
  __syncthreads();
  float xpr[2][2][4];  // [mf][nfl][r]: m = m0+mf*16+lrow, n = ncol0+nfl*16+quad*4+r
  {
    f32x4 xacc[2][2] = {};
    ksweep(&x_bf[(size_t)(m0 + lrow) * 1024 + quad * 8],
           &x_bf[(size_t)(m0 + 16 + lrow) * 1024 + quad * 8], wslw, xacc);
#pragma unroll
    for (int nfl = 0; nfl < 2; ++nfl) {
      float4 bin4 = *(const float4*)&b_in[ncol0 + nfl * 16 + quad * 4];
#pragma unroll
      for (int mf = 0; mf < 2; ++mf)
#pragma unroll
        for (int r = 0; r < 4; ++r)
          xpr[mf][nfl][r] = xacc[mf][nfl][r] + ((const float*)&bin4)[r];
    }
  }
  __syncthreads();  // all ws (Wi) reads done

  // ---- Wr slice -> ws (resident for all steps) ----
  load_ws(Wr + (size_t)n0 * 1024, ws, tid);

  // ---- resolve group homogeneity (relaxed MALL reads only; no acquire) ----
  if (tid == 0) {
    while (__hip_atomic_load(ctr + 1, __ATOMIC_RELAXED, __HIP_MEMORY_SCOPE_AGENT) < 16u)
      __builtin_amdgcn_s_sleep(2);
    asm volatile("" ::: "memory");  // keep mask read after the spin
    unsigned m = __hip_atomic_load(ctr + 2, __ATOMIC_RELAXED, __HIP_MEMORY_SCOPE_AGENT);
    fastflag = ((m & (m - 1u)) == 0u) ? 1u : 0u;
  }

  // ---- t=0: h = tanh(xproj + b_rec), mod(0)=1, h_prev=0 ----
  unsigned short* cur = hA;
  unsigned short* nxt = hB;
#pragma unroll
  for (int mf = 0; mf < 2; ++mf)
#pragma unroll
    for (int nfl = 0; nfl < 2; ++nfl) {
      float h0 = tanh_fast(xpr[mf][nfl][0] + ((const float*)&brec4[nfl])[0]);
      float h1 = tanh_fast(xpr[mf][nfl][1] + ((const float*)&brec4[nfl])[1]);
      float h2 = tanh_fast(xpr[mf][nfl][2] + ((const float*)&brec4[nfl])[2]);
      float h3 = tanh_fast(xpr[mf][nfl][3] + ((const float*)&brec4[nfl])[3]);
      uint2 pk = {cvt_pk_bf16(h0, h1), cvt_pk_bf16(h2, h3)};
      *(uint2*)&cur[(size_t)(m0 + mf * 16 + lrow) * 1024 + ncol0 + nfl * 16 + quad * 4] = pk;
    }
  __syncthreads();  // ws (Wr) ready + fastflag published
  const bool fastp = (fastflag != 0u);

  // ---- steps t = 1..29 ----
#pragma unroll 1
  for (int t = 1; t < 30; ++t) {
    if (fastp) group_barrier_l2(ctr, 16u * (unsigned)t);  // h(t-1) via XCD L2
    else       group_barrier(ctr, 16u * (unsigned)t);     // device-scope fallback
    const float mod = mods.m[t];
    f32x4 acc[2][2] = {};
    ksweep(&cur[(size_t)(m0 + lrow) * 1024 + quad * 8],
           &cur[(size_t)(m0 + 16 + lrow) * 1024 + quad * 8], wslw, acc);
#pragma unroll
    for (int mf = 0; mf < 2; ++mf)
#pragma unroll
      for (int nfl = 0; nfl < 2; ++nfl) {
        float h0 = tanh_fast(xpr[mf][nfl][0] +
                             (acc[mf][nfl][0] + ((const float*)&brec4[nfl])[0]) * mod);
        float h1 = tanh_fast(xpr[mf][nfl][1] +
                             (acc[mf][nfl][1] + ((const float*)&brec4[nfl])[1]) * mod);
        float h2 = tanh_fast(xpr[mf][nfl][2] +
                             (acc[mf][nfl][2] + ((const float*)&brec4[nfl])[2]) * mod);
        float h3 = tanh_fast(xpr[mf][nfl][3] +
                             (acc[mf][nfl][3] + ((const float*)&brec4[nfl])[3]) * mod);
        uint2 pk = {cvt_pk_bf16(h0, h1), cvt_pk_bf16(h2, h3)};
        *(uint2*)&nxt[(size_t)(m0 + mf * 16 + lrow) * 1024 + ncol0 + nfl * 16 + quad * 4] = pk;
      }
    unsigned short* tmp = cur; cur = nxt; nxt = tmp;
  }
  // h29 ends in hB (odd number of steps after t=0); kernel-end dispatch
  // release fence writes back dirty L2 for gemm_bt0.
}

extern "C" void kernel_launch(void* const* d_in, const int* in_sizes, int n_in,
                              void* d_out, int out_size, void* d_ws, size_t ws_size,
                              hipStream_t stream) {
  const float* x     = (const float*)d_in[0];
  const float* W_in  = (const float*)d_in[1];
  const float* b_in  = (const float*)d_in[2];
  const float* W_rec = (const float*)d_in[3];
  const float* b_rec = (const float*)d_in[4];
  const float* W_out = (const float*)d_in[5];
  const float* b_out = (const float*)d_in[6];
  const float* u_in  = (const float*)d_in[7];
  const float* u_rec = (const float*)d_in[8];
  const float* u_out = (const float*)d_in[9];

  const int B = 4096, H = 1024, DOUT = 256;

  char* w = (char*)d_ws;
  float* S = (float*)w;                          // 256 floats
  float* v = S + 256;                            // 3 x 1024 floats
  unsigned* bar = (unsigned*)(w + 14336);        // 16 groups x 128 B
  unsigned short* Wi_bf = (unsigned short*)(w + (1 << 14));
  unsigned short* Wr_bf = Wi_bf + (size_t)H * H;
  unsigned short* Wo_bf = Wr_bf + (size_t)H * H;
  unsigned short* x_bf  = Wo_bf + (size_t)DOUT * H;
  unsigned short* hA = x_bf + (size_t)B * H;
  unsigned short* hB = hA + (size_t)B * H;

  hipMemsetAsync(w, 0, 1 << 14, stream);  // zero S, v, barrier counters+masks

  dim3 t256(256);
  spec_col3<<<dim3(4, 16, 3), t256, 0, stream>>>(W_in, W_rec, W_out, u_in, u_rec, u_out, v);
  norm3<<<3, t256, 0, stream>>>(v, S);
  rowsq3<<<2304, t256, 0, stream>>>(W_in, W_rec, W_out, v, S);
  spec_finalize<<<1, 64, 0, stream>>>(S);
  cvt_all<<<1024, t256, 0, stream>>>((const float4*)W_in, (const float4*)W_rec,
                                     (const float4*)W_out, (const float4*)x, S,
                                     (ushort4*)Wi_bf, (ushort4*)Wr_bf,
                                     (ushort4*)Wo_bf, (ushort4*)x_bf);

  Mods mods;
  for (int t = 0; t < 32; ++t) mods.m[t] = (float)(1.0 + 0.1 * sin(0.3 * (double)t));
  {
    void* args[] = {(void*)&x_bf, (void*)&Wi_bf, (void*)&Wr_bf, (void*)&b_in,
                    (void*)&b_rec, (void*)&hA, (void*)&hB, (void*)&bar, (void*)&mods};
    hipLaunchCooperativeKernel((const void*)rnn_coop, dim3(256), dim3(1024),
                               args, 0, stream);
  }

  // out = h29 @ Wo_n^T + b_out
  gemm_bt0<<<dim3(B / 64, DOUT / 128), t256, 0, stream>>>(
      hB, Wo_bf, b_out, (float*)d_out, B, DOUT, H);
}

// Round 10
// 1353.017 us; speedup vs baseline: 1.0594x; 1.0594x over previous
//
#include <hip/hip_runtime.h>
#include <hip/hip_bf16.h>
#include <math.h>
#include <stdint.h>

// HolomorphicEqProp: B=4096, D_IN=H=1024, D_OUT=256, steps=30.
// Round-19: ILP shape at fixed occupancy (the TLP axis is CLOSED by
// register arithmetic: R18's VGPR_Count=64 + 1GB HBM traffic = forced
// spill at 4 waves/SIMD; latency-hiding state needs ~230 VGPR -> 2
// waves/SIMD @ 256 VGPR is the operating point).
//  - Wave partition of the 256x64 block re-shaped 8x(32Mx64N) ->
//    4x2 waves of (64M x 32N): per pair {4 ds_read_b128 -> 16 MFMA}
//    (ds:MFMA 1:2 -> 1:4; LDS/CU/step 1MB -> 0.5MB), 4 a-streams x
//    ring-8 = 32 outstanding global loads, lead ~560 cyc (fat pairs).
//  - VGPR ~230 under __launch_bounds__(512,1); h rows read by 2 waves
//    on the same CU (L1 dedup expected — FETCH is the check).
//  - Periphery: norm3+rowsq3 fused into reduce3; spec_finalize inlined
//    into cvt_all (-2 launches).
//  Everything else VERBATIM R16 (passed, 647us): tiled conflict-free
//  LDS, R10 XCD-L2 lockstep barrier + agent fallback, swapped-operand
//  MFMA D-layout, cvt_pk epilogue, tanh_fast, setprio.

#define EPSF 1e-12f

typedef short bf16x8 __attribute__((ext_vector_type(8)));
typedef float f32x4 __attribute__((ext_vector_type(4)));

struct Mods { float m[32]; };

__device__ __forceinline__ unsigned short f2bf(float f) {
  union { float f; unsigned u; } v; v.f = f;
  unsigned r = v.u + 0x7FFFu + ((v.u >> 16) & 1u);  // RNE
  return (unsigned short)(r >> 16);
}

// packed f32x2 -> bf16x2 (RNE), single VALU op
__device__ __forceinline__ unsigned cvt_pk_bf16(float lo, float hi) {
  unsigned r;
  asm("v_cvt_pk_bf16_f32 %0, %1, %2" : "=v"(r) : "v"(lo), "v"(hi));
  return r;
}

// tanh(x) = 1 - 2/(exp(2x)+1). Saturates exactly; abs err ~1e-7 << bf16 eps.
__device__ __forceinline__ float tanh_fast(float x) {
  float e = __expf(2.0f * x);
  float r = __builtin_amdgcn_rcpf(e + 1.0f);
  return fmaf(-2.0f, r, 1.0f);
}

// async global->LDS (only in gemm_bt0: R1-validated pattern)
__device__ __forceinline__ void async16(const void* g, void* l) {
  __builtin_amdgcn_global_load_lds(
      (__attribute__((address_space(1))) void*)(uintptr_t)(g),
      (__attribute__((address_space(3))) void*)(unsigned)(uintptr_t)(l),
      16, 0, 0);
}

__device__ __forceinline__ float block_reduce_sum(float x) {
#pragma unroll
  for (int o = 32; o > 0; o >>= 1) x += __shfl_down(x, o, 64);
  __shared__ float sm[8];
  int lane = threadIdx.x & 63, w = threadIdx.x >> 6;
  if (lane == 0) sm[w] = x;
  __syncthreads();
  float t = 0.f;
  if (threadIdx.x == 0) {
    int nw = (int)(blockDim.x >> 6);
    for (int i = 0; i < nw; ++i) t += sm[i];
  }
  return t;
}

// ---------------- fused spectral-norm setup (fp32, exact) ----------------

__global__ void spec_col3(const float* __restrict__ Wi, const float* __restrict__ Wr,
                          const float* __restrict__ Wo, const float* __restrict__ ui,
                          const float* __restrict__ ur, const float* __restrict__ uo,
                          float* __restrict__ v) {
  int z = blockIdx.z;
  const float* W = (z == 0) ? Wi : (z == 1) ? Wr : Wo;
  const float* u = (z == 0) ? ui : (z == 1) ? ur : uo;
  int M = (z == 2) ? 256 : 1024;
  int i0 = blockIdx.y * 64;
  if (i0 >= M) return;
  int j = blockIdx.x * blockDim.x + threadIdx.x;
  float acc = 0.f;
  for (int i = i0; i < i0 + 64; ++i)
    acc += W[(size_t)i * 1024 + j] * u[i];
  atomicAdd(&v[z * 1024 + j], acc);
}

// Fused: blocks 0..2303 = rowsq3 work (S[3+z] += (row.v)^2),
//        blocks 2304..2306 = norm3 work (S[z] = ||v||^2).
// Both depend only on v (spec_col3); no intra-kernel ordering needed.
__global__ void reduce3(const float* __restrict__ Wi, const float* __restrict__ Wr,
                        const float* __restrict__ Wo, const float* __restrict__ v,
                        float* __restrict__ S) {
  int bid = blockIdx.x;
  if (bid >= 2304) {
    int z = bid - 2304;
    float acc = 0.f;
    for (int i = threadIdx.x; i < 1024; i += blockDim.x) {
      float x = v[z * 1024 + i];
      acc += x * x;
    }
    float t = block_reduce_sum(acc);
    if (threadIdx.x == 0) S[z] = t;
    return;
  }
  int z = (bid < 1024) ? 0 : (bid < 2048) ? 1 : 2;
  int row = bid - ((z == 0) ? 0 : (z == 1) ? 1024 : 2048);
  const float* W = (z == 0) ? Wi : (z == 1) ? Wr : Wo;
  const float* vv = v + z * 1024;
  float acc = 0.f;
  for (int j = threadIdx.x; j < 1024; j += blockDim.x)
    acc += W[(size_t)row * 1024 + j] * vv[j];
  float r = block_reduce_sum(acc);
  if (threadIdx.x == 0) atomicAdd(&S[3 + z], r * r);
}

__device__ __forceinline__ ushort4 cvt4e(float4 w, float s) {
  ushort4 r;
  r.x = f2bf(w.x * s); r.y = f2bf(w.y * s); r.z = f2bf(w.z * s); r.w = f2bf(w.w * s);
  return r;
}

// sigma^-1 from the reduce3 outputs (exact spec_finalize math, inlined)
__device__ __forceinline__ float inv_sigma(float nvsq, float wv2) {
  float nv = sqrtf(nvsq);
  float inv = 1.f / (nv + EPSF);
  float u2sq = wv2 * inv * inv;
  float nu = sqrtf(u2sq);
  float sigma = u2sq / (nu + EPSF);
  return 1.f / sigma;
}

__global__ void cvt_all(const float4* __restrict__ Wi, const float4* __restrict__ Wr,
                        const float4* __restrict__ Wo, const float4* __restrict__ x,
                        const float* __restrict__ S,
                        ushort4* __restrict__ oWi, ushort4* __restrict__ oWr,
                        ushort4* __restrict__ oWo, ushort4* __restrict__ ox) {
  float s6 = inv_sigma(S[0], S[3]);
  float s7 = inv_sigma(S[1], S[4]);
  float s8 = inv_sigma(S[2], S[5]);
  int stride = gridDim.x * blockDim.x;
  int t0 = blockIdx.x * blockDim.x + threadIdx.x;
  for (int i = t0; i < 262144; i += stride) oWi[i] = cvt4e(Wi[i], s6);
  for (int i = t0; i < 262144; i += stride) oWr[i] = cvt4e(Wr[i], s7);
  for (int i = t0; i < 65536; i += stride) oWo[i] = cvt4e(Wo[i], s8);
  for (int i = t0; i < 1048576; i += stride) ox[i] = cvt4e(x[i], 1.0f);
}

// C = A[M,K] . B[N,K]^T + bias[n], fp32 out. 64x128 tile (validated R5/R7).
__global__ __launch_bounds__(256) void gemm_bt0(
    const unsigned short* __restrict__ A, const unsigned short* __restrict__ B,
    const float* __restrict__ bias, float* __restrict__ outF,
    int M, int N, int K) {
  constexpr int BM = 64, BN = 128, BK = 32;
  __shared__ __align__(16) unsigned short As[BM * BK];
  __shared__ __align__(16) unsigned short Bs[BN * BK];
  const int tid = threadIdx.x;
  const int wave = tid >> 6, lane = tid & 63;
  const int m0 = blockIdx.x * BM, n0 = blockIdx.y * BN;
  const int wm = (wave >> 1) * 32, wn = (wave & 1) * 64;
  const int lrow = lane & 15, quad = lane >> 4;

  f32x4 acc[2][4] = {};

  for (int k0 = 0; k0 < K; k0 += BK) {
    {
      int e = tid * 8;
      int r = e >> 5, c = e & 31;
      async16(&A[(size_t)(m0 + r) * K + k0 + c], &As[e]);
#pragma unroll
      for (int inst = 0; inst < 2; ++inst) {
        int eb = inst * 2048 + tid * 8;
        int rb = eb >> 5, cb = eb & 31;
        async16(&B[(size_t)(n0 + rb) * K + k0 + cb], &Bs[eb]);
      }
    }
    __syncthreads();

    bf16x8 af[2], bfr[4];
#pragma unroll
    for (int i = 0; i < 2; ++i)
      af[i] = *(const bf16x8*)&As[(wm + i * 16 + lrow) * BK + quad * 8];
#pragma unroll
    for (int j = 0; j < 4; ++j)
      bfr[j] = *(const bf16x8*)&Bs[(wn + j * 16 + lrow) * BK + quad * 8];
#pragma unroll
    for (int i = 0; i < 2; ++i)
#pragma unroll
      for (int j = 0; j < 4; ++j)
        acc[i][j] = __builtin_amdgcn_mfma_f32_16x16x32_bf16(af[i], bfr[j], acc[i][j], 0, 0, 0);
    __syncthreads();
  }

#pragma unroll
  for (int i = 0; i < 2; ++i)
#pragma unroll
    for (int j = 0; j < 4; ++j) {
      int col = n0 + wn + j * 16 + lrow;
      float bv = bias[col];
#pragma unroll
      for (int r = 0; r < 4; ++r) {
        int row = m0 + wm + i * 16 + quad * 4 + r;
        outF[(size_t)row * N + col] = acc[i][j][r] + bv;
      }
    }
}

// ---------------- cooperative RNN ----------------

// Tiled conflict-free LDS (R16-validated, verbatim): ws[nf][kc][lane][8],
// nf 0..3, kc 0..31; subtile (nf,kc) = rows nf*16..+15, cols kc*32..+31 of
// the 64x1024 slice, 1 KB contiguous, lane l reads bytes l*16..+15.
__device__ __forceinline__ void load_ws(const unsigned short* __restrict__ src,
                                        unsigned short* ws, int tid) {
  int r = tid & 63, s = tid >> 6;
  int nf = r >> 4, lrow = r & 15;
  const unsigned short* p = src + (size_t)r * 1024 + s * 128;
#pragma unroll
  for (int j = 0; j < 16; ++j) {
    int c = s * 128 + j * 8;
    int kc = c >> 5, quad = (c >> 3) & 3;
    *(bf16x8*)&ws[((nf * 32 + kc) * 64 + (lrow + 16 * quad)) * 8] =
        *(const bf16x8*)(p + j * 8);
  }
}

// K-sweep, wave tile 64M x 32N: acc[4][2], 4 a-streams x ring-8, per pair
// {4 ds_read_b128 -> 16 MFMA} (ds:MFMA = 1:4). wslw = ws + lane*8 +
// nw*32768; nfl-1 offset = 16384 shorts. All indices compile-time (#20).
__device__ __forceinline__ void ksweep(const unsigned short* __restrict__ a0p,
                                       const unsigned short* __restrict__ a1p,
                                       const unsigned short* __restrict__ a2p,
                                       const unsigned short* __restrict__ a3p,
                                       const unsigned short* wslw,
                                       f32x4 acc[4][2]) {
  bf16x8 pa0[8], pa1[8], pa2[8], pa3[8];
#pragma unroll
  for (int i = 0; i < 8; ++i) {
    pa0[i] = *(const bf16x8*)(a0p + i * 32);
    pa1[i] = *(const bf16x8*)(a1p + i * 32);
    pa2[i] = *(const bf16x8*)(a2p + i * 32);
    pa3[i] = *(const bf16x8*)(a3p + i * 32);
  }
#pragma unroll 1
  for (int kb = 0; kb < 32; kb += 8) {
#define PAIR(OFF)                                                                \
    {                                                                            \
      const int kc0 = kb + (OFF), kc1 = kc0 + 1;                                 \
      bf16x8 b00 = *(const bf16x8*)(wslw + kc0 * 512);                           \
      bf16x8 b10 = *(const bf16x8*)(wslw + 16384 + kc0 * 512);                   \
      bf16x8 b01 = *(const bf16x8*)(wslw + kc1 * 512);                           \
      bf16x8 b11 = *(const bf16x8*)(wslw + 16384 + kc1 * 512);                   \
      bf16x8 s0 = pa0[(OFF) & 7], s1 = pa1[(OFF) & 7];                           \
      bf16x8 s2 = pa2[(OFF) & 7], s3 = pa3[(OFF) & 7];                           \
      bf16x8 t0 = pa0[((OFF) + 1) & 7], t1 = pa1[((OFF) + 1) & 7];               \
      bf16x8 t2 = pa2[((OFF) + 1) & 7], t3 = pa3[((OFF) + 1) & 7];               \
      pa0[(OFF) & 7] = *(const bf16x8*)(a0p + ((kc0 + 8) & 31) * 32);            \
      pa1[(OFF) & 7] = *(const bf16x8*)(a1p + ((kc0 + 8) & 31) * 32);            \
      pa2[(OFF) & 7] = *(const bf16x8*)(a2p + ((kc0 + 8) & 31) * 32);            \
      pa3[(OFF) & 7] = *(const bf16x8*)(a3p + ((kc0 + 8) & 31) * 32);            \
      pa0[((OFF) + 1) & 7] = *(const bf16x8*)(a0p + ((kc1 + 8) & 31) * 32);      \
      pa1[((OFF) + 1) & 7] = *(const bf16x8*)(a1p + ((kc1 + 8) & 31) * 32);      \
      pa2[((OFF) + 1) & 7] = *(const bf16x8*)(a2p + ((kc1 + 8) & 31) * 32);      \
      pa3[((OFF) + 1) & 7] = *(const bf16x8*)(a3p + ((kc1 + 8) & 31) * 32);      \
      __builtin_amdgcn_s_setprio(1);                                             \
      acc[0][0] = __builtin_amdgcn_mfma_f32_16x16x32_bf16(b00, s0, acc[0][0], 0, 0, 0); \
      acc[1][0] = __builtin_amdgcn_mfma_f32_16x16x32_bf16(b00, s1, acc[1][0], 0, 0, 0); \
      acc[2][0] = __builtin_amdgcn_mfma_f32_16x16x32_bf16(b00, s2, acc[2][0], 0, 0, 0); \
      acc[3][0] = __builtin_amdgcn_mfma_f32_16x16x32_bf16(b00, s3, acc[3][0], 0, 0, 0); \
      acc[0][1] = __builtin_amdgcn_mfma_f32_16x16x32_bf16(b10, s0, acc[0][1], 0, 0, 0); \
      acc[1][1] = __builtin_amdgcn_mfma_f32_16x16x32_bf16(b10, s1, acc[1][1], 0, 0, 0); \
      acc[2][1] = __builtin_amdgcn_mfma_f32_16x16x32_bf16(b10, s2, acc[2][1], 0, 0, 0); \
      acc[3][1] = __builtin_amdgcn_mfma_f32_16x16x32_bf16(b10, s3, acc[3][1], 0, 0, 0); \
      acc[0][0] = __builtin_amdgcn_mfma_f32_16x16x32_bf16(b01, t0, acc[0][0], 0, 0, 0); \
      acc[1][0] = __builtin_amdgcn_mfma_f32_16x16x32_bf16(b01, t1, acc[1][0], 0, 0, 0); \
      acc[2][0] = __builtin_amdgcn_mfma_f32_16x16x32_bf16(b01, t2, acc[2][0], 0, 0, 0); \
      acc[3][0] = __builtin_amdgcn_mfma_f32_16x16x32_bf16(b01, t3, acc[3][0], 0, 0, 0); \
      acc[0][1] = __builtin_amdgcn_mfma_f32_16x16x32_bf16(b11, t0, acc[0][1], 0, 0, 0); \
      acc[1][1] = __builtin_amdgcn_mfma_f32_16x16x32_bf16(b11, t1, acc[1][1], 0, 0, 0); \
      acc[2][1] = __builtin_amdgcn_mfma_f32_16x16x32_bf16(b11, t2, acc[2][1], 0, 0, 0); \
      acc[3][1] = __builtin_amdgcn_mfma_f32_16x16x32_bf16(b11, t3, acc[3][1], 0, 0, 0); \
      __builtin_amdgcn_s_setprio(0);                                             \
    }
    PAIR(0) PAIR(2) PAIR(4) PAIR(6)
#undef PAIR
  }
}

// ---- slow/fallback barrier (agent scope, R9-validated form) ----
__device__ __forceinline__ void group_barrier(unsigned* ctr, unsigned target) {
  __syncthreads();  // all waves' stores issued & drained to L2
  if (threadIdx.x == 0) {
    __hip_atomic_fetch_add(ctr, 1u, __ATOMIC_RELEASE, __HIP_MEMORY_SCOPE_AGENT);
    while (__hip_atomic_load(ctr, __ATOMIC_RELAXED, __HIP_MEMORY_SCOPE_AGENT) < target)
      __builtin_amdgcn_s_sleep(2);
    (void)__hip_atomic_load(ctr, __ATOMIC_ACQUIRE, __HIP_MEMORY_SCOPE_AGENT);
  }
  __syncthreads();
}

// ---- fast barrier (group verified XCD-homogeneous): h stays in XCD L2 ----
// (R10-validated: WRITE_SIZE 246 MB -> 22 MB.) Relaxed MALL signal/poll, one
// L1-only invalidate (buffer_inv sc0) on the consumer.
__device__ __forceinline__ void group_barrier_l2(unsigned* ctr, unsigned target) {
  __syncthreads();  // h stores of all 8 waves now visible in XCD L2
  if (threadIdx.x == 0) {
    __hip_atomic_fetch_add(ctr, 1u, __ATOMIC_RELAXED, __HIP_MEMORY_SCOPE_AGENT);
    while (__hip_atomic_load(ctr, __ATOMIC_RELAXED, __HIP_MEMORY_SCOPE_AGENT) < target)
      __builtin_amdgcn_s_sleep(2);
    asm volatile("buffer_inv sc0" ::: "memory");  // invalidate this CU's L1 only
  }
  __syncthreads();
}

// 256 blocks x 512 threads, 1 block/CU (LDS 128KB), 8 waves = 2/SIMD.
// Block (mt,nt): mt = (bid&7)*2+((bid>>3)&1), nt = bid>>4 (R16 mapping).
// M rows [mt*256,+256), N cols [nt*64,+64). Wave w: m-sub (w&3)*64
// (64 rows), n-sub (w>>2)*32 (32 cols). Group = blocks sharing mt
// (bid&15), closed under the h dependency, swizzled onto one XCD.
// Barrier slot layout (128 B): [0]=step ctr, [1]=publish, [2]=XCD mask.
__global__ __launch_bounds__(512, 1) void rnn_coop(
    const unsigned short* __restrict__ x_bf,  // [4096][1024] bf16
    const unsigned short* __restrict__ Wi,    // [1024][1024] bf16 (scaled)
    const unsigned short* __restrict__ Wr,    // [1024][1024] bf16 (scaled)
    const float* __restrict__ b_in,
    const float* __restrict__ b_rec,
    unsigned short* __restrict__ hA,
    unsigned short* __restrict__ hB,
    unsigned* __restrict__ bar,
    Mods mods) {
  __shared__ __align__(16) unsigned short ws[4 * 32 * 512];  // 128 KB tiled
  __shared__ unsigned fastflag;

  const int tid = threadIdx.x;
  const int w = tid >> 6, lane = tid & 63;
  const int lrow = lane & 15, quad = lane >> 4;
  const int mw = w & 3, nw = w >> 2;   // wave m-sub (0..3), n-sub (0..1)
  const int bid = (int)blockIdx.x;
  const int mt = (bid & 7) * 2 + ((bid >> 3) & 1);
  const int nt = bid >> 4;
  const int gid = bid & 15;
  const int m0 = mt * 256 + mw * 64;
  const int n0 = nt * 64;
  const int ncol0 = n0 + nw * 32;      // wave's first output column
  unsigned* ctr = bar + gid * 32;      // 128 B per group
  const unsigned short* wslw = ws + lane * 8 + nw * 32768;  // per-wave base

  // ---- publish this block's physical XCD at entry (R10 protocol) ----
  if (tid == 0) {
    unsigned xcc;
    asm volatile("s_getreg_b32 %0, hwreg(HW_REG_XCC_ID)" : "=s"(xcc));
    __hip_atomic_fetch_or(ctr + 2, 1u << (xcc & 15u), __ATOMIC_RELAXED,
                          __HIP_MEMORY_SCOPE_AGENT);
    __hip_atomic_fetch_add(ctr + 1, 1u, __ATOMIC_RELEASE, __HIP_MEMORY_SCOPE_AGENT);
  }

  // per-lane biases: n = ncol0 + nfl*16 + quad*4 + r  (swapped D-layout)
  float4 brec4[2];
#pragma unroll
  for (int nfl = 0; nfl < 2; ++nfl)
    brec4[nfl] = *(const float4*)&b_rec[ncol0 + nfl * 16 + quad * 4];

  // ---- phase A: xproj slice (registers) via Wi slice in ws ----
  load_ws(Wi + (size_t)n0 * 1024, ws, tid);
  __syncthreads();
  float xpr[4][2][4];  // [mf][nfl][r]: m = m0+mf*16+lrow, n = ncol0+nfl*16+quad*4+r
  {
    f32x4 xacc[4][2] = {};
    ksweep(&x_bf[(size_t)(m0 + lrow) * 1024 + quad * 8],
           &x_bf[(size_t)(m0 + 16 + lrow) * 1024 + quad * 8],
           &x_bf[(size_t)(m0 + 32 + lrow) * 1024 + quad * 8],
           &x_bf[(size_t)(m0 + 48 + lrow) * 1024 + quad * 8], wslw, xacc);
#pragma unroll
    for (int nfl = 0; nfl < 2; ++nfl) {
      float4 bin4 = *(const float4*)&b_in[ncol0 + nfl * 16 + quad * 4];
#pragma unroll
      for (int mf = 0; mf < 4; ++mf)
#pragma unroll
        for (int r = 0; r < 4; ++r)
          xpr[mf][nfl][r] = xacc[mf][nfl][r] + ((const float*)&bin4)[r];
    }
  }
  __syncthreads();  // all ws (Wi) reads done

  // ---- Wr slice -> ws (resident for all steps) ----
  load_ws(Wr + (size_t)n0 * 1024, ws, tid);

  // ---- resolve group homogeneity (relaxed MALL reads only; no acquire) ----
  if (tid == 0) {
    while (__hip_atomic_load(ctr + 1, __ATOMIC_RELAXED, __HIP_MEMORY_SCOPE_AGENT) < 16u)
      __builtin_amdgcn_s_sleep(2);
    asm volatile("" ::: "memory");  // keep mask read after the spin
    unsigned m = __hip_atomic_load(ctr + 2, __ATOMIC_RELAXED, __HIP_MEMORY_SCOPE_AGENT);
    fastflag = ((m & (m - 1u)) == 0u) ? 1u : 0u;
  }

  // ---- t=0: h = tanh(xproj + b_rec), mod(0)=1, h_prev=0 ----
  unsigned short* cur = hA;
  unsigned short* nxt = hB;
#pragma unroll
  for (int mf = 0; mf < 4; ++mf)
#pragma unroll
    for (int nfl = 0; nfl < 2; ++nfl) {
      float h0 = tanh_fast(xpr[mf][nfl][0] + ((const float*)&brec4[nfl])[0]);
      float h1 = tanh_fast(xpr[mf][nfl][1] + ((const float*)&brec4[nfl])[1]);
      float h2 = tanh_fast(xpr[mf][nfl][2] + ((const float*)&brec4[nfl])[2]);
      float h3 = tanh_fast(xpr[mf][nfl][3] + ((const float*)&brec4[nfl])[3]);
      uint2 pk = {cvt_pk_bf16(h0, h1), cvt_pk_bf16(h2, h3)};
      *(uint2*)&cur[(size_t)(m0 + mf * 16 + lrow) * 1024 + ncol0 + nfl * 16 + quad * 4] = pk;
    }
  __syncthreads();  // ws (Wr) ready + fastflag published
  const bool fastp = (fastflag != 0u);

  // ---- steps t = 1..29 ----
#pragma unroll 1
  for (int t = 1; t < 30; ++t) {
    if (fastp) group_barrier_l2(ctr, 16u * (unsigned)t);  // h(t-1) via XCD L2
    else       group_barrier(ctr, 16u * (unsigned)t);     // device-scope fallback
    const float mod = mods.m[t];
    f32x4 acc[4][2] = {};
    ksweep(&cur[(size_t)(m0 + lrow) * 1024 + quad * 8],
           &cur[(size_t)(m0 + 16 + lrow) * 1024 + quad * 8],
           &cur[(size_t)(m0 + 32 + lrow) * 1024 + quad * 8],
           &cur[(size_t)(m0 + 48 + lrow) * 1024 + quad * 8], wslw, acc);
#pragma unroll
    for (int mf = 0; mf < 4; ++mf)
#pragma unroll
      for (int nfl = 0; nfl < 2; ++nfl) {
        float h0 = tanh_fast(xpr[mf][nfl][0] +
                             (acc[mf][nfl][0] + ((const float*)&brec4[nfl])[0]) * mod);
        float h1 = tanh_fast(xpr[mf][nfl][1] +
                             (acc[mf][nfl][1] + ((const float*)&brec4[nfl])[1]) * mod);
        float h2 = tanh_fast(xpr[mf][nfl][2] +
                             (acc[mf][nfl][2] + ((const float*)&brec4[nfl])[2]) * mod);
        float h3 = tanh_fast(xpr[mf][nfl][3] +
                             (acc[mf][nfl][3] + ((const float*)&brec4[nfl])[3]) * mod);
        uint2 pk = {cvt_pk_bf16(h0, h1), cvt_pk_bf16(h2, h3)};
        *(uint2*)&nxt[(size_t)(m0 + mf * 16 + lrow) * 1024 + ncol0 + nfl * 16 + quad * 4] = pk;
      }
    unsigned short* tmp = cur; cur = nxt; nxt = tmp;
  }
  // h29 ends in hB (odd number of steps after t=0); kernel-end dispatch
  // release fence writes back dirty L2 for gemm_bt0.
}

extern "C" void kernel_launch(void* const* d_in, const int* in_sizes, int n_in,
                              void* d_out, int out_size, void* d_ws, size_t ws_size,
                              hipStream_t stream) {
  const float* x     = (const float*)d_in[0];
  const float* W_in  = (const float*)d_in[1];
  const float* b_in  = (const float*)d_in[2];
  const float* W_rec = (const float*)d_in[3];
  const float* b_rec = (const float*)d_in[4];
  const float* W_out = (const float*)d_in[5];
  const float* b_out = (const float*)d_in[6];
  const float* u_in  = (const float*)d_in[7];
  const float* u_rec = (const float*)d_in[8];
  const float* u_out = (const float*)d_in[9];

  const int B = 4096, H = 1024, DOUT = 256;

  char* w = (char*)d_ws;
  float* S = (float*)w;                          // 256 floats
  float* v = S + 256;                            // 3 x 1024 floats
  unsigned* bar = (unsigned*)(w + 14336);        // 16 groups x 128 B
  unsigned short* Wi_bf = (unsigned short*)(w + (1 << 14));
  unsigned short* Wr_bf = Wi_bf + (size_t)H * H;
  unsigned short* Wo_bf = Wr_bf + (size_t)H * H;
  unsigned short* x_bf  = Wo_bf + (size_t)DOUT * H;
  unsigned short* hA = x_bf + (size_t)B * H;
  unsigned short* hB = hA + (size_t)B * H;

  hipMemsetAsync(w, 0, 1 << 14, stream);  // zero S, v, barrier counters+masks

  dim3 t256(256);
  spec_col3<<<dim3(4, 16, 3), t256, 0, stream>>>(W_in, W_rec, W_out, u_in, u_rec, u_out, v);
  reduce3<<<2307, t256, 0, stream>>>(W_in, W_rec, W_out, v, S);
  cvt_all<<<1024, t256, 0, stream>>>((const float4*)W_in, (const float4*)W_rec,
                                     (const float4*)W_out, (const float4*)x, S,
                                     (ushort4*)Wi_bf, (ushort4*)Wr_bf,
                                     (ushort4*)Wo_bf, (ushort4*)x_bf);

  Mods mods;
  for (int t = 0; t < 32; ++t) mods.m[t] = (float)(1.0 + 0.1 * sin(0.3 * (double)t));
  {
    void* args[] = {(void*)&x_bf, (void*)&Wi_bf, (void*)&Wr_bf, (void*)&b_in,
                    (void*)&b_rec, (void*)&hA, (void*)&hB, (void*)&bar, (void*)&mods};
    hipLaunchCooperativeKernel((const void*)rnn_coop, dim3(256), dim3(512),
                               args, 0, stream);
  }

  // out = h29 @ Wo_n^T + b_out
  gemm_bt0<<<dim3(B / 64, DOUT / 128), t256, 0, stream>>>(
      hB, Wo_bf, b_out, (float*)d_out, B, DOUT, H);
}

// Round 11
// 680.313 us; speedup vs baseline: 2.1069x; 1.9888x over previous
//
#include <hip/hip_runtime.h>
#include <hip/hip_bf16.h>
#include <math.h>
#include <stdint.h>

// HolomorphicEqProp: B=4096, D_IN=H=1024, D_OUT=256, steps=30.
// Round-20: STRUCTURAL restructure. The recurrence is ROW-independent:
// h(t)[m] = tanh(xpr[m] + (h(t-1)[m] @ Wr^T)*mod). The old design's
// column-partition (and all its XCD/barrier machinery) existed only to
// keep a 64-col Wr slice in LDS. Inverted: 128 blocks x 32 batch rows,
// h lives in LDS (2x64KB ping-pong), Wr (2MB, read-only, XCD-L2-resident)
// is STREAMED as pre-tiled MFMA fragments global->reg each step.
//  - No cooperative launch, no inter-block sync, 1 __syncthreads/step.
//  - Weights & x pre-tiled by cvt_all into the R16-verified frag layout:
//    frag(nf,kc) = 512 shorts, lane l holds bytes l*16..+15
//    (row n&15 = lrow, cols (k>>3)&3 = quad slot).
//  - 4-set modulo-scheduled {2 h-ds_read + NF w-global} pipeline, lead ~3
//    sets; per step per wave 512 MFMA; acc+xpr ~160 VGPR, total ~220.
//  - Output GEMM fused (stream Wo the same way) -> gemm_bt0 + 16MB h
//    round-trip deleted.
//  Floors/step: Wr stream 7.4us (XCD-L2) .. 15us (per-CU port), MFMA
//  8.3us, h-LDS 5.6us, overlapped -> 9-15us/step vs R16's 21.6.

#define EPSF 1e-12f

typedef short bf16x8 __attribute__((ext_vector_type(8)));
typedef float f32x4 __attribute__((ext_vector_type(4)));

struct Mods { float m[32]; };

__device__ __forceinline__ unsigned short f2bf(float f) {
  union { float f; unsigned u; } v; v.f = f;
  unsigned r = v.u + 0x7FFFu + ((v.u >> 16) & 1u);  // RNE
  return (unsigned short)(r >> 16);
}

// packed f32x2 -> bf16x2 (RNE), single VALU op
__device__ __forceinline__ unsigned cvt_pk_bf16(float lo, float hi) {
  unsigned r;
  asm("v_cvt_pk_bf16_f32 %0, %1, %2" : "=v"(r) : "v"(lo), "v"(hi));
  return r;
}

// tanh(x) = 1 - 2/(exp(2x)+1). Saturates exactly; abs err ~1e-7 << bf16 eps.
__device__ __forceinline__ float tanh_fast(float x) {
  float e = __expf(2.0f * x);
  float r = __builtin_amdgcn_rcpf(e + 1.0f);
  return fmaf(-2.0f, r, 1.0f);
}

__device__ __forceinline__ float block_reduce_sum(float x) {
#pragma unroll
  for (int o = 32; o > 0; o >>= 1) x += __shfl_down(x, o, 64);
  __shared__ float sm[8];
  int lane = threadIdx.x & 63, w = threadIdx.x >> 6;
  if (lane == 0) sm[w] = x;
  __syncthreads();
  float t = 0.f;
  if (threadIdx.x == 0) {
    int nw = (int)(blockDim.x >> 6);
    for (int i = 0; i < nw; ++i) t += sm[i];
  }
  return t;
}

// ---------------- fused spectral-norm setup (fp32, exact) ----------------

__global__ void spec_col3(const float* __restrict__ Wi, const float* __restrict__ Wr,
                          const float* __restrict__ Wo, const float* __restrict__ ui,
                          const float* __restrict__ ur, const float* __restrict__ uo,
                          float* __restrict__ v) {
  int z = blockIdx.z;
  const float* W = (z == 0) ? Wi : (z == 1) ? Wr : Wo;
  const float* u = (z == 0) ? ui : (z == 1) ? ur : uo;
  int M = (z == 2) ? 256 : 1024;
  int i0 = blockIdx.y * 64;
  if (i0 >= M) return;
  int j = blockIdx.x * blockDim.x + threadIdx.x;
  float acc = 0.f;
  for (int i = i0; i < i0 + 64; ++i)
    acc += W[(size_t)i * 1024 + j] * u[i];
  atomicAdd(&v[z * 1024 + j], acc);
}

// Fused norm+rowsq (R19-validated): blocks 0..2303 rowsq, 2304..2306 norms.
__global__ void reduce3(const float* __restrict__ Wi, const float* __restrict__ Wr,
                        const float* __restrict__ Wo, const float* __restrict__ v,
                        float* __restrict__ S) {
  int bid = blockIdx.x;
  if (bid >= 2304) {
    int z = bid - 2304;
    float acc = 0.f;
    for (int i = threadIdx.x; i < 1024; i += blockDim.x) {
      float x = v[z * 1024 + i];
      acc += x * x;
    }
    float t = block_reduce_sum(acc);
    if (threadIdx.x == 0) S[z] = t;
    return;
  }
  int z = (bid < 1024) ? 0 : (bid < 2048) ? 1 : 2;
  int row = bid - ((z == 0) ? 0 : (z == 1) ? 1024 : 2048);
  const float* W = (z == 0) ? Wi : (z == 1) ? Wr : Wo;
  const float* vv = v + z * 1024;
  float acc = 0.f;
  for (int j = threadIdx.x; j < 1024; j += blockDim.x)
    acc += W[(size_t)row * 1024 + j] * vv[j];
  float r = block_reduce_sum(acc);
  if (threadIdx.x == 0) atomicAdd(&S[3 + z], r * r);
}

__device__ __forceinline__ ushort4 cvt4e(float4 w, float s) {
  ushort4 r;
  r.x = f2bf(w.x * s); r.y = f2bf(w.y * s); r.z = f2bf(w.z * s); r.w = f2bf(w.w * s);
  return r;
}

// sigma^-1 (exact spec_finalize math, inlined; R19-validated)
__device__ __forceinline__ float inv_sigma(float nvsq, float wv2) {
  float nv = sqrtf(nvsq);
  float inv = 1.f / (nv + EPSF);
  float u2sq = wv2 * inv * inv;
  float nu = sqrtf(u2sq);
  float sigma = u2sq / (nu + EPSF);
  return 1.f / sigma;
}

// Tiled-output conversion. Weight frag layout (R16-verified lane pattern):
// dst_u4 = ((nf*32 + kc)*64 + lrow + 16*quad)*2 + j4 with nf=n>>4,
// lrow=n&15, kc=k>>5, quad=(k>>3)&3, j4=(k>>2)&1 (k = 4*u4 index in row).
// x tiled per 32-row block: blk stride 8192 u4, mf=(m>>4)&1.
__global__ void cvt_all(const float4* __restrict__ Wi, const float4* __restrict__ Wr,
                        const float4* __restrict__ Wo, const float4* __restrict__ x,
                        const float* __restrict__ S,
                        ushort4* __restrict__ oWi, ushort4* __restrict__ oWr,
                        ushort4* __restrict__ oWo, ushort4* __restrict__ ox) {
  float s6 = inv_sigma(S[0], S[3]);
  float s7 = inv_sigma(S[1], S[4]);
  float s8 = inv_sigma(S[2], S[5]);
  int stride = gridDim.x * blockDim.x;
  int t0 = blockIdx.x * blockDim.x + threadIdx.x;
  for (int i = t0; i < 262144; i += stride) {  // Wi: 1024 rows
    int n = i >> 8, ku = i & 255;
    int kc = ku >> 3, quad = (ku >> 1) & 3, j4 = ku & 1;
    oWi[(((n >> 4) * 32 + kc) * 64 + (n & 15) + 16 * quad) * 2 + j4] = cvt4e(Wi[i], s6);
  }
  for (int i = t0; i < 262144; i += stride) {  // Wr: 1024 rows
    int n = i >> 8, ku = i & 255;
    int kc = ku >> 3, quad = (ku >> 1) & 3, j4 = ku & 1;
    oWr[(((n >> 4) * 32 + kc) * 64 + (n & 15) + 16 * quad) * 2 + j4] = cvt4e(Wr[i], s7);
  }
  for (int i = t0; i < 65536; i += stride) {   // Wo: 256 rows
    int n = i >> 8, ku = i & 255;
    int kc = ku >> 3, quad = (ku >> 1) & 3, j4 = ku & 1;
    oWo[(((n >> 4) * 32 + kc) * 64 + (n & 15) + 16 * quad) * 2 + j4] = cvt4e(Wo[i], s8);
  }
  for (int i = t0; i < 1048576; i += stride) { // x: 4096 rows, block-tiled
    int m = i >> 8, ku = i & 255;
    int kc = ku >> 3, quad = (ku >> 1) & 3, j4 = ku & 1;
    ox[(size_t)(m >> 5) * 8192 +
       ((((m >> 4) & 1) * 32 + kc) * 64 + (m & 15) + 16 * quad) * 2 + j4] =
        cvt4e(x[i], 1.0f);
  }
}

// ---------------- fused streaming RNN (one block = 32 batch rows) --------

// K-sweep: B-operand h frags (2 mf) from hsrc (LDS tiled or global tiled x),
// A-operand W frags (NF) streamed from global tiled weights. 4-set modulo
// schedule: prologue loads kc 0..3; each STEP does 2*NF MFMA on set S then
// reissues set S for kc+S+4 (lead ~3 sets). All reg indices compile-time.
template <int NF>
__device__ __forceinline__ void sweepT(const unsigned short* hsrc,
                                       const unsigned short* __restrict__ Wsrc,
                                       int lx, f32x4 acc[2][NF]) {
  bf16x8 hf[4][2], wf[4][NF];
#define LOADSET(S, KC)                                                      \
  {                                                                         \
    int kq = (KC) & 31;                                                     \
    hf[S][0] = *(const bf16x8*)(hsrc + kq * 512 + lx);                      \
    hf[S][1] = *(const bf16x8*)(hsrc + (32 + kq) * 512 + lx);               \
    _Pragma("unroll")                                                       \
    for (int nf = 0; nf < NF; ++nf)                                         \
      wf[S][nf] = *(const bf16x8*)(Wsrc + (nf * 32 + kq) * 512 + lx);       \
  }
  LOADSET(0, 0) LOADSET(1, 1) LOADSET(2, 2) LOADSET(3, 3)
#pragma unroll 1
  for (int kc = 0; kc < 32; kc += 4) {
#define STEP(S)                                                             \
    {                                                                       \
      __builtin_amdgcn_s_setprio(1);                                        \
      _Pragma("unroll")                                                     \
      for (int nf = 0; nf < NF; ++nf) {                                     \
        acc[0][nf] = __builtin_amdgcn_mfma_f32_16x16x32_bf16(               \
            wf[S][nf], hf[S][0], acc[0][nf], 0, 0, 0);                      \
        acc[1][nf] = __builtin_amdgcn_mfma_f32_16x16x32_bf16(               \
            wf[S][nf], hf[S][1], acc[1][nf], 0, 0, 0);                      \
      }                                                                     \
      __builtin_amdgcn_s_setprio(0);                                        \
      LOADSET(S, kc + S + 4)                                                \
    }
    STEP(0) STEP(1) STEP(2) STEP(3)
#undef STEP
  }
#undef LOADSET
}

// 128 blocks x 512 threads (8 waves = 2/SIMD, ~220 VGPR). Block owns batch
// rows [blk*32, +32); h (tiled frags) ping-pongs in LDS; Wr streamed from
// XCD L2 each step. Wave w owns n-cols [w*128,+128) for the recurrence
// (2 halves of 4 nf) and [w*32,+32) for the fused output GEMM.
__global__ __launch_bounds__(512, 1) void rnn_all(
    const unsigned short* __restrict__ xT,   // tiled x
    const unsigned short* __restrict__ WiT,  // tiled Wi (scaled bf16)
    const unsigned short* __restrict__ WrT,  // tiled Wr
    const unsigned short* __restrict__ WoT,  // tiled Wo
    const float* __restrict__ b_in,
    const float* __restrict__ b_rec,
    const float* __restrict__ b_out,
    float* __restrict__ outF,
    Mods mods) {
  __shared__ __align__(16) unsigned short hb[2 * 32768];  // 2 x 64 KB tiled

  const int tid = threadIdx.x;
  const int w = tid >> 6, lane = tid & 63;
  const int lrow = lane & 15, quad = lane >> 4;
  const int lx = lane * 8;
  const int m0 = (int)blockIdx.x * 32;
  const unsigned short* xb = xT + (size_t)blockIdx.x * 32768;

  // ---- xproj: xpr[nh][mf][nf] = x @ Wi^T + b_in (streamed, x from global) ----
  f32x4 xpr[2][2][4];
#pragma unroll
  for (int nh = 0; nh < 2; ++nh) {
    f32x4 xa[2][4] = {};
    sweepT<4>(xb, WiT + (size_t)((w * 8 + nh * 4) * 32) * 512, lx, xa);
#pragma unroll
    for (int nf = 0; nf < 4; ++nf) {
      float4 bin4 = *(const float4*)&b_in[w * 128 + nh * 64 + nf * 16 + quad * 4];
#pragma unroll
      for (int mf = 0; mf < 2; ++mf) {
        xpr[nh][mf][nf][0] = xa[mf][nf][0] + bin4.x;
        xpr[nh][mf][nf][1] = xa[mf][nf][1] + bin4.y;
        xpr[nh][mf][nf][2] = xa[mf][nf][2] + bin4.z;
        xpr[nh][mf][nf][3] = xa[mf][nf][3] + bin4.w;
      }
    }
  }

  // ---- recurrence: t=0 (no sweep) then t=1..29, h ping-pong in LDS ----
  unsigned short* hcur = hb;
  unsigned short* hnxt = hb + 32768;
#pragma unroll 1
  for (int t = 0; t < 30; ++t) {
    const float mod = mods.m[t];
#pragma unroll
    for (int nh = 0; nh < 2; ++nh) {
      f32x4 acc[2][4] = {};
      if (t) sweepT<4>(hcur, WrT + (size_t)((w * 8 + nh * 4) * 32) * 512, lx, acc);
#pragma unroll
      for (int nf = 0; nf < 4; ++nf) {
        float4 br4 = *(const float4*)&b_rec[w * 128 + nh * 64 + nf * 16 + quad * 4];
        // write address: element (m=m0+mf*16+lrow, n) as next step's B-frag:
        // kc' = w*4+nh*2+(nf>>1); lane' = lrow+16*((nf*2+(quad>>1))&3); j0=(quad&1)*4
        const int kcp = w * 4 + nh * 2 + (nf >> 1);
        const int lanep = lrow + 16 * ((nf * 2 + (quad >> 1)) & 3);
#pragma unroll
        for (int mf = 0; mf < 2; ++mf) {
          float h0 = tanh_fast(fmaf(acc[mf][nf][0] + br4.x, mod, xpr[nh][mf][nf][0]));
          float h1 = tanh_fast(fmaf(acc[mf][nf][1] + br4.y, mod, xpr[nh][mf][nf][1]));
          float h2 = tanh_fast(fmaf(acc[mf][nf][2] + br4.z, mod, xpr[nh][mf][nf][2]));
          float h3 = tanh_fast(fmaf(acc[mf][nf][3] + br4.w, mod, xpr[nh][mf][nf][3]));
          uint2 pk = {cvt_pk_bf16(h0, h1), cvt_pk_bf16(h2, h3)};
          *(uint2*)(hnxt + (mf * 32 + kcp) * 512 + lanep * 8 + (quad & 1) * 4) = pk;
        }
      }
    }
    __syncthreads();  // h(t) complete & visible block-wide
    unsigned short* tmp = hcur; hcur = hnxt; hnxt = tmp;
  }

  // ---- fused output GEMM: out = h29 @ Wo^T + b_out (h29 in hcur) ----
  {
    f32x4 ao[2][2] = {};
    sweepT<2>(hcur, WoT + (size_t)((w * 2) * 32) * 512, lx, ao);
#pragma unroll
    for (int nf = 0; nf < 2; ++nf) {
      float4 bo4 = *(const float4*)&b_out[w * 32 + nf * 16 + quad * 4];
#pragma unroll
      for (int mf = 0; mf < 2; ++mf) {
        float4 o;
        o.x = ao[mf][nf][0] + bo4.x;
        o.y = ao[mf][nf][1] + bo4.y;
        o.z = ao[mf][nf][2] + bo4.z;
        o.w = ao[mf][nf][3] + bo4.w;
        *(float4*)&outF[(size_t)(m0 + mf * 16 + lrow) * 256 + w * 32 + nf * 16 + quad * 4] = o;
      }
    }
  }
}

extern "C" void kernel_launch(void* const* d_in, const int* in_sizes, int n_in,
                              void* d_out, int out_size, void* d_ws, size_t ws_size,
                              hipStream_t stream) {
  const float* x     = (const float*)d_in[0];
  const float* W_in  = (const float*)d_in[1];
  const float* b_in  = (const float*)d_in[2];
  const float* W_rec = (const float*)d_in[3];
  const float* b_rec = (const float*)d_in[4];
  const float* W_out = (const float*)d_in[5];
  const float* b_out = (const float*)d_in[6];
  const float* u_in  = (const float*)d_in[7];
  const float* u_rec = (const float*)d_in[8];
  const float* u_out = (const float*)d_in[9];

  const int B = 4096, H = 1024;

  char* w = (char*)d_ws;
  float* S = (float*)w;                              // 256 floats
  float* v = S + 256;                                // 3 x 1024 floats
  unsigned short* WiT = (unsigned short*)(w + 16384);      // 1M shorts (2 MB)
  unsigned short* WrT = WiT + (size_t)H * H;               // 1M shorts
  unsigned short* WoT = WrT + (size_t)H * H;               // 256K shorts
  unsigned short* xT  = WoT + (size_t)256 * H;             // 4M shorts (8 MB)

  hipMemsetAsync(w, 0, 16384, stream);  // zero S, v

  dim3 t256(256);
  spec_col3<<<dim3(4, 16, 3), t256, 0, stream>>>(W_in, W_rec, W_out, u_in, u_rec, u_out, v);
  reduce3<<<2307, t256, 0, stream>>>(W_in, W_rec, W_out, v, S);
  cvt_all<<<1024, t256, 0, stream>>>((const float4*)W_in, (const float4*)W_rec,
                                     (const float4*)W_out, (const float4*)x, S,
                                     (ushort4*)WiT, (ushort4*)WrT,
                                     (ushort4*)WoT, (ushort4*)xT);

  Mods mods;
  for (int t = 0; t < 32; ++t) mods.m[t] = (float)(1.0 + 0.1 * sin(0.3 * (double)t));

  rnn_all<<<dim3(B / 32), dim3(512), 0, stream>>>(
      xT, WiT, WrT, WoT, b_in, b_rec, b_out, (float*)d_out, mods);
}

// Round 12
// 603.259 us; speedup vs baseline: 2.3760x; 1.1277x over previous
//
#include <hip/hip_runtime.h>
#include <hip/hip_bf16.h>
#include <math.h>
#include <stdint.h>

// HolomorphicEqProp: B=4096, D_IN=H=1024, D_OUT=256, steps=30.
// Round-21: R20 streaming structure + pair N-split to use all 256 CUs.
//  R20 counters: occupancy 11.7% (128 blocks = half the GPU), per-CU L2
//  port bound (2MB Wr/step/CU -> 14.8us floor, measured 18.8, 79%).
//  R21: 256 blocks = 128 pairs x 2 halves. Block (p,s): batch rows
//  [p*32,+32), h-cols [s*512,+512). Per-CU Wr stream 1MB/step (port floor
//  7.4us). h in GLOBAL tiled ping-pong images (128KB/pair, XCD-L2-resident,
//  NO LDS): each block writes its kc-range of the shared image (disjoint),
//  __syncthreads drains to L2 (R10/R13-validated), relaxed MALL flag;
//  consumer spins + buffer_inv sc0. bid = s*128+p => both halves of a pair
//  on one XCD under round-robin (runtime-verified via XCC publish;
//  release/acquire fallback). The t-entry wait (partner>=t) is also the
//  WAR guard for parity reuse (skew<=1 by flag ordering).
//  VGPR ~200 under __launch_bounds__(512,2) (cap 256; R19's spill was a
//  128-cap with ~280 live). Output GEMM fused (h29 image parity 1).

#define EPSF 1e-12f

typedef short bf16x8 __attribute__((ext_vector_type(8)));
typedef float f32x4 __attribute__((ext_vector_type(4)));

struct Mods { float m[32]; };

__device__ __forceinline__ unsigned short f2bf(float f) {
  union { float f; unsigned u; } v; v.f = f;
  unsigned r = v.u + 0x7FFFu + ((v.u >> 16) & 1u);  // RNE
  return (unsigned short)(r >> 16);
}

// packed f32x2 -> bf16x2 (RNE), single VALU op
__device__ __forceinline__ unsigned cvt_pk_bf16(float lo, float hi) {
  unsigned r;
  asm("v_cvt_pk_bf16_f32 %0, %1, %2" : "=v"(r) : "v"(lo), "v"(hi));
  return r;
}

// tanh(x) = 1 - 2/(exp(2x)+1). Saturates exactly; abs err ~1e-7 << bf16 eps.
__device__ __forceinline__ float tanh_fast(float x) {
  float e = __expf(2.0f * x);
  float r = __builtin_amdgcn_rcpf(e + 1.0f);
  return fmaf(-2.0f, r, 1.0f);
}

__device__ __forceinline__ float block_reduce_sum(float x) {
#pragma unroll
  for (int o = 32; o > 0; o >>= 1) x += __shfl_down(x, o, 64);
  __shared__ float sm[8];
  int lane = threadIdx.x & 63, w = threadIdx.x >> 6;
  if (lane == 0) sm[w] = x;
  __syncthreads();
  float t = 0.f;
  if (threadIdx.x == 0) {
    int nw = (int)(blockDim.x >> 6);
    for (int i = 0; i < nw; ++i) t += sm[i];
  }
  return t;
}

// ---------------- fused spectral-norm setup (fp32, exact) ----------------

__global__ void spec_col3(const float* __restrict__ Wi, const float* __restrict__ Wr,
                          const float* __restrict__ Wo, const float* __restrict__ ui,
                          const float* __restrict__ ur, const float* __restrict__ uo,
                          float* __restrict__ v) {
  int z = blockIdx.z;
  const float* W = (z == 0) ? Wi : (z == 1) ? Wr : Wo;
  const float* u = (z == 0) ? ui : (z == 1) ? ur : uo;
  int M = (z == 2) ? 256 : 1024;
  int i0 = blockIdx.y * 64;
  if (i0 >= M) return;
  int j = blockIdx.x * blockDim.x + threadIdx.x;
  float acc = 0.f;
  for (int i = i0; i < i0 + 64; ++i)
    acc += W[(size_t)i * 1024 + j] * u[i];
  atomicAdd(&v[z * 1024 + j], acc);
}

// Fused norm+rowsq (R19-validated): blocks 0..2303 rowsq, 2304..2306 norms.
__global__ void reduce3(const float* __restrict__ Wi, const float* __restrict__ Wr,
                        const float* __restrict__ Wo, const float* __restrict__ v,
                        float* __restrict__ S) {
  int bid = blockIdx.x;
  if (bid >= 2304) {
    int z = bid - 2304;
    float acc = 0.f;
    for (int i = threadIdx.x; i < 1024; i += blockDim.x) {
      float x = v[z * 1024 + i];
      acc += x * x;
    }
    float t = block_reduce_sum(acc);
    if (threadIdx.x == 0) S[z] = t;
    return;
  }
  int z = (bid < 1024) ? 0 : (bid < 2048) ? 1 : 2;
  int row = bid - ((z == 0) ? 0 : (z == 1) ? 1024 : 2048);
  const float* W = (z == 0) ? Wi : (z == 1) ? Wr : Wo;
  const float* vv = v + z * 1024;
  float acc = 0.f;
  for (int j = threadIdx.x; j < 1024; j += blockDim.x)
    acc += W[(size_t)row * 1024 + j] * vv[j];
  float r = block_reduce_sum(acc);
  if (threadIdx.x == 0) atomicAdd(&S[3 + z], r * r);
}

__device__ __forceinline__ ushort4 cvt4e(float4 w, float s) {
  ushort4 r;
  r.x = f2bf(w.x * s); r.y = f2bf(w.y * s); r.z = f2bf(w.z * s); r.w = f2bf(w.w * s);
  return r;
}

// sigma^-1 (exact spec_finalize math, inlined; R19-validated)
__device__ __forceinline__ float inv_sigma(float nvsq, float wv2) {
  float nv = sqrtf(nvsq);
  float inv = 1.f / (nv + EPSF);
  float u2sq = wv2 * inv * inv;
  float nu = sqrtf(u2sq);
  float sigma = u2sq / (nu + EPSF);
  return 1.f / sigma;
}

// Tiled-output conversion (R20-validated, byte-identical).
__global__ void cvt_all(const float4* __restrict__ Wi, const float4* __restrict__ Wr,
                        const float4* __restrict__ Wo, const float4* __restrict__ x,
                        const float* __restrict__ S,
                        ushort4* __restrict__ oWi, ushort4* __restrict__ oWr,
                        ushort4* __restrict__ oWo, ushort4* __restrict__ ox) {
  float s6 = inv_sigma(S[0], S[3]);
  float s7 = inv_sigma(S[1], S[4]);
  float s8 = inv_sigma(S[2], S[5]);
  int stride = gridDim.x * blockDim.x;
  int t0 = blockIdx.x * blockDim.x + threadIdx.x;
  for (int i = t0; i < 262144; i += stride) {  // Wi: 1024 rows
    int n = i >> 8, ku = i & 255;
    int kc = ku >> 3, quad = (ku >> 1) & 3, j4 = ku & 1;
    oWi[(((n >> 4) * 32 + kc) * 64 + (n & 15) + 16 * quad) * 2 + j4] = cvt4e(Wi[i], s6);
  }
  for (int i = t0; i < 262144; i += stride) {  // Wr: 1024 rows
    int n = i >> 8, ku = i & 255;
    int kc = ku >> 3, quad = (ku >> 1) & 3, j4 = ku & 1;
    oWr[(((n >> 4) * 32 + kc) * 64 + (n & 15) + 16 * quad) * 2 + j4] = cvt4e(Wr[i], s7);
  }
  for (int i = t0; i < 65536; i += stride) {   // Wo: 256 rows
    int n = i >> 8, ku = i & 255;
    int kc = ku >> 3, quad = (ku >> 1) & 3, j4 = ku & 1;
    oWo[(((n >> 4) * 32 + kc) * 64 + (n & 15) + 16 * quad) * 2 + j4] = cvt4e(Wo[i], s8);
  }
  for (int i = t0; i < 1048576; i += stride) { // x: 4096 rows, block-tiled
    int m = i >> 8, ku = i & 255;
    int kc = ku >> 3, quad = (ku >> 1) & 3, j4 = ku & 1;
    ox[(size_t)(m >> 5) * 8192 +
       ((((m >> 4) & 1) * 32 + kc) * 64 + (m & 15) + 16 * quad) * 2 + j4] =
        cvt4e(x[i], 1.0f);
  }
}

// ---------------- fused streaming RNN (pair-split, no LDS) ---------------

// K-sweep (R20-validated shape): B-operand h frags (2 mf) from hsrc (global
// tiled image or tiled x), A-operand W frags (NF) streamed from global
// tiled weights. 4-set modulo schedule, lead ~3 sets. All indices
// compile-time (rule #20).
template <int NF>
__device__ __forceinline__ void sweepT(const unsigned short* hsrc,
                                       const unsigned short* __restrict__ Wsrc,
                                       int lx, f32x4 acc[2][NF]) {
  bf16x8 hf[4][2], wf[4][NF];
#define LOADSET(S, KC)                                                      \
  {                                                                         \
    int kq = (KC) & 31;                                                     \
    hf[S][0] = *(const bf16x8*)(hsrc + kq * 512 + lx);                      \
    hf[S][1] = *(const bf16x8*)(hsrc + (32 + kq) * 512 + lx);               \
    _Pragma("unroll")                                                       \
    for (int nf = 0; nf < NF; ++nf)                                         \
      wf[S][nf] = *(const bf16x8*)(Wsrc + (nf * 32 + kq) * 512 + lx);       \
  }
  LOADSET(0, 0) LOADSET(1, 1) LOADSET(2, 2) LOADSET(3, 3)
#pragma unroll 1
  for (int kc = 0; kc < 32; kc += 4) {
#define STEP(S)                                                             \
    {                                                                       \
      __builtin_amdgcn_s_setprio(1);                                        \
      _Pragma("unroll")                                                     \
      for (int nf = 0; nf < NF; ++nf) {                                     \
        acc[0][nf] = __builtin_amdgcn_mfma_f32_16x16x32_bf16(               \
            wf[S][nf], hf[S][0], acc[0][nf], 0, 0, 0);                      \
        acc[1][nf] = __builtin_amdgcn_mfma_f32_16x16x32_bf16(               \
            wf[S][nf], hf[S][1], acc[1][nf], 0, 0, 0);                      \
      }                                                                     \
      __builtin_amdgcn_s_setprio(0);                                        \
      LOADSET(S, kc + S + 4)                                                \
    }
    STEP(0) STEP(1) STEP(2) STEP(3)
#undef STEP
  }
#undef LOADSET
}

// 256 blocks x 512 threads (8 waves = 2/SIMD). bid = s*128 + p:
// pair p (batch rows [p*32,+32)), half s (h-cols [s*512,+512)).
// Round-robin => XCD(bid) = bid&7 = p&7 for both halves (runtime-checked).
// h: global tiled images himg[p][parity] (64KB each; full 1024 cols,
// halves written disjointly by the two blocks). Wave w: cols
// [s*512 + w*64, +64) for recurrence, [s*128 + w*16, +16) for output.
__global__ __launch_bounds__(512, 2) void rnn_all(
    const unsigned short* __restrict__ xT,   // tiled x (per 32-row block)
    const unsigned short* __restrict__ WiT,  // tiled Wi (scaled bf16)
    const unsigned short* __restrict__ WrT,  // tiled Wr
    const unsigned short* __restrict__ WoT,  // tiled Wo
    const float* __restrict__ b_in,
    const float* __restrict__ b_rec,
    const float* __restrict__ b_out,
    unsigned short* __restrict__ himg,       // 128 pairs x 2 x 32768 shorts
    unsigned* __restrict__ flags,            // (p*2+s)*16 u32 stride (64B)
    unsigned* __restrict__ xcds,             // p*2+s
    float* __restrict__ outF,
    Mods mods) {
  const int tid = threadIdx.x;
  const int w = tid >> 6, lane = tid & 63;
  const int lrow = lane & 15, quad = lane >> 4;
  const int lx = lane * 8;
  const int bid = (int)blockIdx.x;
  const int p = bid & 127, s = bid >> 7;
  const int m0 = p * 32;
  const int nfbase = s * 32 + w * 4;        // Wr/Wi frag-row base for wave
  unsigned short* img0 = himg + (size_t)p * 65536;
  unsigned short* img1 = img0 + 32768;
  unsigned* myflag = flags + (size_t)(p * 2 + s) * 16;
  unsigned* ptflag = flags + (size_t)(p * 2 + (1 - s)) * 16;
  const unsigned short* xb = xT + (size_t)p * 32768;

  unsigned myxcc = 0;
  if (tid == 0) {
    asm volatile("s_getreg_b32 %0, hwreg(HW_REG_XCC_ID)" : "=s"(myxcc));
    // RELEASE: xcd publish drained before any later flag is observable.
    __hip_atomic_store(xcds + (p * 2 + s), myxcc, __ATOMIC_RELEASE,
                       __HIP_MEMORY_SCOPE_AGENT);
  }

  // per-lane biases for this wave's 64 recurrence cols
  float4 brec4[4];
#pragma unroll
  for (int nf = 0; nf < 4; ++nf)
    brec4[nf] = *(const float4*)&b_rec[s * 512 + w * 64 + nf * 16 + quad * 4];

  // ---- xproj: xpr[mf][nf] = (x @ Wi^T + b_in) for own 512 cols ----
  f32x4 xpr[2][4];
  {
    f32x4 xa[2][4] = {};
    sweepT<4>(xb, WiT + (size_t)nfbase * 32 * 512, lx, xa);
#pragma unroll
    for (int nf = 0; nf < 4; ++nf) {
      float4 bin4 = *(const float4*)&b_in[s * 512 + w * 64 + nf * 16 + quad * 4];
#pragma unroll
      for (int mf = 0; mf < 2; ++mf) {
        xpr[mf][nf][0] = xa[mf][nf][0] + bin4.x;
        xpr[mf][nf][1] = xa[mf][nf][1] + bin4.y;
        xpr[mf][nf][2] = xa[mf][nf][2] + bin4.z;
        xpr[mf][nf][3] = xa[mf][nf][3] + bin4.w;
      }
    }
  }

  int fastv = 1;  // meaningful in tid0 only; decided at t==1

  // ---- t = 0..29: compute h(t) into img[t&1] (own kc range) ----
#pragma unroll 1
  for (int t = 0; t < 30; ++t) {
    f32x4 acc[2][4] = {};
    if (t) {
      if (tid == 0) {
        while (__hip_atomic_load(ptflag, __ATOMIC_RELAXED,
                                 __HIP_MEMORY_SCOPE_AGENT) < (unsigned)t)
          __builtin_amdgcn_s_sleep(2);
        if (t == 1) {
          unsigned px = __hip_atomic_load(xcds + (p * 2 + (1 - s)),
                                          __ATOMIC_RELAXED, __HIP_MEMORY_SCOPE_AGENT);
          fastv = ((px & 15u) == (myxcc & 15u)) ? 1 : 0;
        }
        if (fastv) {
          asm volatile("buffer_inv sc0" ::: "memory");  // L1 only; h in XCD L2
        } else {
          (void)__hip_atomic_load(ptflag, __ATOMIC_ACQUIRE, __HIP_MEMORY_SCOPE_AGENT);
        }
      }
      __syncthreads();  // partner h(t-1) visible to all waves
      sweepT<4>((t & 1) ? img0 : img1, WrT + (size_t)nfbase * 32 * 512, lx, acc);
    }
    const float mod = mods.m[t];
    unsigned short* dst = (t & 1) ? img1 : img0;
#pragma unroll
    for (int nf = 0; nf < 4; ++nf) {
      // write own h as next step's B-frag (R20-validated mapping, kc
      // rebased to the pair image): ncol = s*512 + w*64 + nf*16 + quad*4+r
      const int kcp = s * 16 + w * 2 + (nf >> 1);
      const int lanep = lrow + 16 * (((nf & 1) * 2 + (quad >> 1)));
#pragma unroll
      for (int mf = 0; mf < 2; ++mf) {
        float h0 = tanh_fast(fmaf(acc[mf][nf][0] + brec4[nf].x, mod, xpr[mf][nf][0]));
        float h1 = tanh_fast(fmaf(acc[mf][nf][1] + brec4[nf].y, mod, xpr[mf][nf][1]));
        float h2 = tanh_fast(fmaf(acc[mf][nf][2] + brec4[nf].z, mod, xpr[mf][nf][2]));
        float h3 = tanh_fast(fmaf(acc[mf][nf][3] + brec4[nf].w, mod, xpr[mf][nf][3]));
        uint2 pk = {cvt_pk_bf16(h0, h1), cvt_pk_bf16(h2, h3)};
        *(uint2*)(dst + (mf * 32 + kcp) * 512 + lanep * 8 + (quad & 1) * 4) = pk;
      }
    }
    __syncthreads();  // all waves' h(t) stores drained to XCD L2
    if (tid == 0) {
      if (t == 0 || !fastv)  // t=0: release also orders the xcd publish path
        __hip_atomic_store(myflag, (unsigned)(t + 1), __ATOMIC_RELEASE,
                           __HIP_MEMORY_SCOPE_AGENT);
      else
        __hip_atomic_store(myflag, (unsigned)(t + 1), __ATOMIC_RELAXED,
                           __HIP_MEMORY_SCOPE_AGENT);
    }
  }

  // ---- fused output GEMM: out = h29 @ Wo^T + b_out (h29 = parity 1) ----
  if (tid == 0) {
    while (__hip_atomic_load(ptflag, __ATOMIC_RELAXED,
                             __HIP_MEMORY_SCOPE_AGENT) < 30u)
      __builtin_amdgcn_s_sleep(2);
    if (fastv) {
      asm volatile("buffer_inv sc0" ::: "memory");
    } else {
      (void)__hip_atomic_load(ptflag, __ATOMIC_ACQUIRE, __HIP_MEMORY_SCOPE_AGENT);
    }
  }
  __syncthreads();
  {
    f32x4 ao[2][1] = {};
    sweepT<1>(img1, WoT + (size_t)((s * 8 + w) * 32) * 512, lx, ao);
    float4 bo4 = *(const float4*)&b_out[s * 128 + w * 16 + quad * 4];
#pragma unroll
    for (int mf = 0; mf < 2; ++mf) {
      float4 o;
      o.x = ao[mf][0][0] + bo4.x;
      o.y = ao[mf][0][1] + bo4.y;
      o.z = ao[mf][0][2] + bo4.z;
      o.w = ao[mf][0][3] + bo4.w;
      *(float4*)&outF[(size_t)(m0 + mf * 16 + lrow) * 256 + s * 128 + w * 16 + quad * 4] = o;
    }
  }
}

extern "C" void kernel_launch(void* const* d_in, const int* in_sizes, int n_in,
                              void* d_out, int out_size, void* d_ws, size_t ws_size,
                              hipStream_t stream) {
  const float* x     = (const float*)d_in[0];
  const float* W_in  = (const float*)d_in[1];
  const float* b_in  = (const float*)d_in[2];
  const float* W_rec = (const float*)d_in[3];
  const float* b_rec = (const float*)d_in[4];
  const float* W_out = (const float*)d_in[5];
  const float* b_out = (const float*)d_in[6];
  const float* u_in  = (const float*)d_in[7];
  const float* u_rec = (const float*)d_in[8];
  const float* u_out = (const float*)d_in[9];

  const int B = 4096, H = 1024;

  char* w = (char*)d_ws;
  float* S = (float*)w;                               // 256 floats
  float* v = S + 256;                                 // 3 x 1024 floats
  unsigned short* WiT = (unsigned short*)(w + 16384); // 1M shorts (2 MB)
  unsigned short* WrT = WiT + (size_t)H * H;          // 1M shorts
  unsigned short* WoT = WrT + (size_t)H * H;          // 256K shorts
  unsigned short* xT  = WoT + (size_t)256 * H;        // 4M shorts (8 MB)
  unsigned short* himg = xT + (size_t)B * H;          // 128*2*32768 shorts (16 MB)
  unsigned* flags = (unsigned*)(himg + (size_t)128 * 2 * 32768);  // 256*64 B
  unsigned* xcds  = flags + 256 * 16;                 // 256 u32

  hipMemsetAsync(w, 0, 16384, stream);                // zero S, v
  hipMemsetAsync(flags, 0, 256 * 64 + 1024, stream);  // zero flags + xcds

  dim3 t256(256);
  spec_col3<<<dim3(4, 16, 3), t256, 0, stream>>>(W_in, W_rec, W_out, u_in, u_rec, u_out, v);
  reduce3<<<2307, t256, 0, stream>>>(W_in, W_rec, W_out, v, S);
  cvt_all<<<1024, t256, 0, stream>>>((const float4*)W_in, (const float4*)W_rec,
                                     (const float4*)W_out, (const float4*)x, S,
                                     (ushort4*)WiT, (ushort4*)WrT,
                                     (ushort4*)WoT, (ushort4*)xT);

  Mods mods;
  for (int t = 0; t < 32; ++t) mods.m[t] = (float)(1.0 + 0.1 * sin(0.3 * (double)t));
  {
    void* args[] = {(void*)&xT, (void*)&WiT, (void*)&WrT, (void*)&WoT,
                    (void*)&b_in, (void*)&b_rec, (void*)&b_out,
                    (void*)&himg, (void*)&flags, (void*)&xcds,
                    (void*)&d_out, (void*)&mods};
    hipLaunchCooperativeKernel((const void*)rnn_all, dim3(256), dim3(512),
                               args, 0, stream);
  }
}